// Round 5
// baseline (386.360 us; speedup 1.0000x reference)
//
#include <hip/hip_runtime.h>
#include <hip/hip_bf16.h>
#include <stdint.h>

typedef __attribute__((ext_vector_type(8))) __bf16 bf16x8;
typedef __attribute__((ext_vector_type(4))) float  f32x4;

// ---------- bf16 helpers (bf16 pairs packed in uint32, little-endian) ----------
__device__ __forceinline__ float bflo(uint32_t p){ return __uint_as_float(p << 16); }
__device__ __forceinline__ float bfhi(uint32_t p){ return __uint_as_float(p & 0xffff0000u); }
__device__ __forceinline__ uint16_t f2bf(float f){
    uint32_t u = __float_as_uint(f);
    uint32_t r = (u + 0x7fffu + ((u >> 16) & 1u)) >> 16;   // RNE
    return (uint16_t)r;
}
__device__ __forceinline__ uint32_t packbf(float a, float b){
    return (uint32_t)f2bf(a) | ((uint32_t)f2bf(b) << 16);
}
__device__ __forceinline__ f32x4 MFMA(bf16x8 a, bf16x8 b, f32x4 c){
    return __builtin_amdgcn_mfma_f32_16x16x32_bf16(a, b, c, 0, 0, 0);
}

// Mean buffer lives in the SECOND HALF of each f32 Emb row (u32 units):
//   Mb(row) = Emb u32 [row*128 + 64, row*128 + 128).
// Xbf (layer-1 bf16 input) lives in the FIRST HALF: Emb u32 [row*128, row*128+64).
#define MB_IDX(row, lane) ((size_t)(row) * 128 + 64 + (lane))

// ---------- CSR build ----------
__global__ void k_deg(const int* __restrict__ dst, int* __restrict__ counts, int E){
    int e = blockIdx.x * 256 + threadIdx.x;
    if (e < E) atomicAdd(&counts[dst[e]], 1);
}

__global__ void k_scan1(const int* __restrict__ counts, int* __restrict__ bsums, int N){
    __shared__ int lds[256];
    int t = threadIdx.x;
    int base = blockIdx.x * 2048 + t * 8;
    int s = 0;
    #pragma unroll
    for (int i = 0; i < 8; ++i){ int idx = base + i; s += (idx < N) ? counts[idx] : 0; }
    lds[t] = s; __syncthreads();
    for (int off = 128; off > 0; off >>= 1){
        if (t < off) lds[t] += lds[t + off];
        __syncthreads();
    }
    if (t == 0) bsums[blockIdx.x] = lds[0];
}

__global__ void k_scan2(int* bsums, int NB){
    int run = 0;
    for (int i = 0; i < NB; ++i){ int v = bsums[i]; bsums[i] = run; run += v; }
}

__global__ void k_scan3(const int* __restrict__ counts, const int* __restrict__ bsums,
                        int* __restrict__ offs, int N){
    __shared__ int lds[256];
    int t = threadIdx.x;
    int base = blockIdx.x * 2048 + t * 8;
    int local[8];
    int s = 0;
    #pragma unroll
    for (int i = 0; i < 8; ++i){
        int idx = base + i;
        int v = (idx < N) ? counts[idx] : 0;
        local[i] = v; s += v;
    }
    lds[t] = s; __syncthreads();
    for (int off = 1; off < 256; off <<= 1){
        int v = (t >= off) ? lds[t - off] : 0;
        __syncthreads();
        lds[t] += v;
        __syncthreads();
    }
    int run = bsums[blockIdx.x] + (lds[t] - s);
    #pragma unroll
    for (int i = 0; i < 8; ++i){
        int idx = base + i;
        if (idx < N){ offs[idx] = run; run += local[i]; }
    }
}

__global__ void k_fill(const int* __restrict__ src, const int* __restrict__ dst,
                       const int* __restrict__ offs, int* __restrict__ cursor,
                       int* __restrict__ ssrc, int E){
    int e = blockIdx.x * 256 + threadIdx.x;
    if (e < E){
        int d = dst[e];
        int p = atomicAdd(&cursor[d], 1);
        ssrc[offs[d] + p] = src[e];
    }
}

// ---------- x -> bf16 hi (into Emb first half) + bf16 lo residual ----------
__global__ __launch_bounds__(256) void k_x2bf(const float* __restrict__ X,
        uint32_t* __restrict__ XbfE, uint32_t* __restrict__ Xlo, int N){
    int i = blockIdx.x * 256 + threadIdx.x;          // 2-pair chunk, total N*32
    if (i >= N * 32) return;
    int row = i >> 5, l = i & 31;
    float4 v = *(const float4*)(X + (size_t)i * 4);
    uint16_t h0 = f2bf(v.x), h1 = f2bf(v.y), h2 = f2bf(v.z), h3 = f2bf(v.w);
    float r0 = v.x - __uint_as_float((uint32_t)h0 << 16);
    float r1 = v.y - __uint_as_float((uint32_t)h1 << 16);
    float r2 = v.z - __uint_as_float((uint32_t)h2 << 16);
    float r3 = v.w - __uint_as_float((uint32_t)h3 << 16);
    uint2 hi; hi.x = (uint32_t)h0 | ((uint32_t)h1 << 16);
    hi.y = (uint32_t)h2 | ((uint32_t)h3 << 16);
    uint2 lo; lo.x = packbf(r0, r1); lo.y = packbf(r2, r3);
    *(uint2*)(XbfE + (size_t)row * 128 + l * 2) = hi;
    *(uint2*)(Xlo  + (size_t)row * 64  + l * 2) = lo;
}

// ---------- weight prep: packed + bank-swizzled layout for LDS staging ----------
// Wpk u16 layout: [kt(8)][sel(2: hi,lo)][slot(512)][e(8)]
//   slot(c,g) = 4*c + (g ^ ((c>>1)&3))   (bank swizzle: octet of lanes -> 8 distinct
//   16B slots -> all 32 banks once per octet on ds_read_b128)
// source: k<128 -> Wl[k][c], k>=128 -> scale*Wr[k-128][c];  k = kt*32 + g*8 + e
__global__ void k_wprep(const float* __restrict__ Wl, const float* __restrict__ Wr,
                        const float* __restrict__ scale,
                        uint16_t* __restrict__ Wpk){
    int idx = blockIdx.x * 256 + threadIdx.x;        // [0, 32768) = c*256 + k
    int c = idx >> 8, k = idx & 255;
    float v;
    if (k < 128){
        v = Wl[k * 128 + c];
    } else {
        v = Wr[(k - 128) * 128 + c];
        if (scale) v *= scale[k - 128];
    }
    uint16_t h = f2bf(v);
    float r = v - __uint_as_float((uint32_t)h << 16);
    int kt = k >> 5, kk = k & 31;
    int g = kk >> 3, e = kk & 7;
    int slot = (c << 2) | (g ^ ((c >> 1) & 3));
    size_t base = (size_t)kt * 8192 + (size_t)slot * 8 + e;
    Wpk[base]        = h;
    Wpk[base + 4096] = f2bf(r);
}

// ---------- neighbor mean: one wave per node; 4 rows per wave-load (uint4) --------
// 16-lane group q loads full 256B row of neighbor (j+q); 8 rows in flight per iter.
// Cross-group shfl reduce at end. MODE 1 folds BN (shift only when cnt>0).
template<int MODE>
__global__ __launch_bounds__(256) void k_agg(
        const uint32_t* __restrict__ Src, int sstr,
        const int* __restrict__ offs, const int* __restrict__ counts,
        const int* __restrict__ ssrc,
        const float* __restrict__ bnscale, const float* __restrict__ bnshift,
        uint32_t* __restrict__ MbBase, int N){
    const int lane = threadIdx.x & 63;
    const int l15  = lane & 15;
    const int q    = lane >> 4;
    int node = blockIdx.x * 4 + (threadIdx.x >> 6);
    if (node >= N) return;
    int cnt = counts[node];
    if (cnt < 0) cnt = 0;
    int off = offs[node];
    const uint32_t* srcb = Src + l15 * 4;
    float a[8];
    #pragma unroll
    for (int i = 0; i < 8; ++i) a[i] = 0.f;

    int j = 0;
    for (; j + 8 <= cnt; j += 8){                     // 8 rows in flight (2 x 4 groups)
        int s0 = ssrc[off + j + q];
        int s1 = ssrc[off + j + 4 + q];
        s0 = (s0 < 0) ? 0 : ((s0 >= N) ? (N - 1) : s0);
        s1 = (s1 < 0) ? 0 : ((s1 >= N) ? (N - 1) : s1);
        uint4 v0 = *(const uint4*)(srcb + (size_t)s0 * sstr);
        uint4 v1 = *(const uint4*)(srcb + (size_t)s1 * sstr);
        a[0] += bflo(v0.x) + bflo(v1.x); a[1] += bfhi(v0.x) + bfhi(v1.x);
        a[2] += bflo(v0.y) + bflo(v1.y); a[3] += bfhi(v0.y) + bfhi(v1.y);
        a[4] += bflo(v0.z) + bflo(v1.z); a[5] += bfhi(v0.z) + bfhi(v1.z);
        a[6] += bflo(v0.w) + bflo(v1.w); a[7] += bfhi(v0.w) + bfhi(v1.w);
    }
    int rem = cnt - j;
    if (rem > 0){
        if (q < rem){
            int s0 = ssrc[off + j + q];
            s0 = (s0 < 0) ? 0 : ((s0 >= N) ? (N - 1) : s0);
            uint4 v0 = *(const uint4*)(srcb + (size_t)s0 * sstr);
            a[0] += bflo(v0.x); a[1] += bfhi(v0.x);
            a[2] += bflo(v0.y); a[3] += bfhi(v0.y);
            a[4] += bflo(v0.z); a[5] += bfhi(v0.z);
            a[6] += bflo(v0.w); a[7] += bfhi(v0.w);
        }
        if (rem > 4 && q < rem - 4){
            int s1 = ssrc[off + j + 4 + q];
            s1 = (s1 < 0) ? 0 : ((s1 >= N) ? (N - 1) : s1);
            uint4 v1 = *(const uint4*)(srcb + (size_t)s1 * sstr);
            a[0] += bflo(v1.x); a[1] += bfhi(v1.x);
            a[2] += bflo(v1.y); a[3] += bfhi(v1.y);
            a[4] += bflo(v1.z); a[5] += bfhi(v1.z);
            a[6] += bflo(v1.w); a[7] += bfhi(v1.w);
        }
    }

    // reduce across the 4 row-groups (lanes l15, l15+16, l15+32, l15+48)
    #pragma unroll
    for (int i = 0; i < 8; ++i){
        a[i] += __shfl_xor(a[i], 16, 64);
        a[i] += __shfl_xor(a[i], 32, 64);
    }
    float inv = 1.0f / fmaxf((float)cnt, 1.0f);
    #pragma unroll
    for (int i = 0; i < 8; ++i) a[i] *= inv;

    if (MODE == 1){
        if (cnt > 0){                                  // ref: zero-degree mean == 0
            int c0 = l15 * 8;
            float4 sc0 = *(const float4*)(bnscale + c0);
            float4 sc1 = *(const float4*)(bnscale + c0 + 4);
            float4 sh0 = *(const float4*)(bnshift + c0);
            float4 sh1 = *(const float4*)(bnshift + c0 + 4);
            a[0] = a[0] * sc0.x + sh0.x; a[1] = a[1] * sc0.y + sh0.y;
            a[2] = a[2] * sc0.z + sh0.z; a[3] = a[3] * sc0.w + sh0.w;
            a[4] = a[4] * sc1.x + sh1.x; a[5] = a[5] * sc1.y + sh1.y;
            a[6] = a[6] * sc1.z + sh1.z; a[7] = a[7] * sc1.w + sh1.w;
        } else {
            #pragma unroll
            for (int i = 0; i < 8; ++i) a[i] = 0.f;
        }
    }

    if (q == 0){
        uint4 o;
        o.x = packbf(a[0], a[1]); o.y = packbf(a[2], a[3]);
        o.z = packbf(a[4], a[5]); o.w = packbf(a[6], a[7]);
        *(uint4*)(MbBase + (size_t)node * 128 + 64 + l15 * 4) = o;
    }
}

// stage one quarter (32 KiB: 4 kt of one sel) of B into sB.
// LDS dest is wave-uniform base (+ lane*16 by HW); global src is per-lane.
__device__ __forceinline__ void stage4(const uint32_t* Wpk, uint32_t (*sB)[2048],
                                       int wid, int lane, int sel, int half){
    #pragma unroll
    for (int i = 0; i < 8; ++i){
        int ch = wid * 8 + i;                        // 32 chunks of 1 KiB
        int ktv = ch >> 3, part = ch & 7;
        __builtin_amdgcn_global_load_lds(
            Wpk + (size_t)(half * 4 + ktv) * 4096 + sel * 2048 + part * 256 + lane * 4,
            &sB[ktv][part * 256], 16, 0, 0);
    }
}

// ---------- MFMA dual-GEMM (K=256 = [mean|own]) + L2-normalize ----------
// Wave owns 32 rows (2 m-tiles), all 128 cols (8 n-tiles).
// All A fragments hoisted to registers up front.  B staged in FOUR 32 KiB
// quarters (hi/lo x K-halves) through one 32 KiB LDS buffer -> 32 KiB/block
// total for 4-5 blocks/CU residency (occupancy was the R3 bottleneck).
// A frag:  lane holds row (lane&15), k = 32*kt + 8*(lane>>4) + e  (contiguous 16B)
// B frag:  swizzled slot; gx = g ^ ((l15>>1)&3)   (conflict-free ds_read_b128)
// C/D:     col = lane&15, row = 4*(lane>>4) + reg   (m89-verified)
// MODE 0: own=Xbf (+Xlo correction on hi); out=relu(norm(.)); Hbf store + BN sums.
// MODE 1: own=Hbf (BN folded into Wpk/bias); out=norm(.); Emb f32 + preds.
template<int MODE>
__global__ __launch_bounds__(256, 4) void k_gemm(
        const uint32_t* Own,                 // MODE0: Xbf in Emb rows (stride 128); MODE1: Hbf (stride 64)
        const uint32_t* OwnLo,               // MODE0 only: Xlo (stride 64; aliases HbfOut)
        const uint32_t* Mb,                  // bf16 means at Emb rows' 2nd half
        const uint32_t* __restrict__ Wpk,    // packed+swizzled [kt][hi/lo][512 slots][8] u16
        const float* __restrict__ bias,      // [128] effective bias
        uint32_t* HbfOut,                    // MODE0 out (aliases OwnLo; alias-safe per-wave)
        float* Emb,                          // MODE1 out (aliases Mb rows; reads precede writes)
        float* __restrict__ bnsum, float* __restrict__ bnsumsq,             // MODE0
        const float* __restrict__ fcW, const float* __restrict__ fcb,       // MODE1
        float* __restrict__ preds, int N){
    __shared__ uint32_t __align__(16) sB[4][2048];   // 32 KiB; reused 4x; aliased by lsum/lsq at end
    const int lane = threadIdx.x & 63;
    const int wid  = threadIdx.x >> 6;
    const int l15  = lane & 15;
    const int g    = lane >> 4;
    const int gx4  = (g ^ ((l15 >> 1) & 3)) * 4;     // swizzled 16B sub-slot (u32 units)
    const int ostr = (MODE == 0) ? 128 : 64;
    const int rowb = blockIdx.x * 128 + wid * 32;    // may be >= N: wave stays for staging

    stage4(Wpk, sB, wid, lane, 0, 0);                // quarter 1: hi, kt 0-3

    int ar0 = rowb + l15;      if (ar0 >= N) ar0 = N - 1;   // clamped dup rows: discarded
    int ar1 = rowb + 16 + l15; if (ar1 >= N) ar1 = N - 1;

    const uint32_t* mp0 = Mb  + (size_t)ar0 * 128 + 64 + g * 4;
    const uint32_t* mp1 = Mb  + (size_t)ar1 * 128 + 64 + g * 4;
    const uint32_t* op0 = Own + (size_t)ar0 * ostr + g * 4;
    const uint32_t* op1 = Own + (size_t)ar1 * ostr + g * 4;

    // hoist ALL A fragments into registers (independent loads, overlap staging)
    bf16x8 am0[4], am1[4], ao0[4], ao1[4];
    #pragma unroll
    for (int kq = 0; kq < 4; ++kq){
        am0[kq] = *(const bf16x8*)(mp0 + kq * 16);
        am1[kq] = *(const bf16x8*)(mp1 + kq * 16);
        ao0[kq] = *(const bf16x8*)(op0 + kq * 16);
        ao1[kq] = *(const bf16x8*)(op1 + kq * 16);
    }
    bf16x8 xl0[4], xl1[4];
    if (MODE == 0){
        #pragma unroll
        for (int kq = 0; kq < 4; ++kq){
            xl0[kq] = *(const bf16x8*)(OwnLo + (size_t)ar0 * 64 + g * 4 + kq * 16);
            xl1[kq] = *(const bf16x8*)(OwnLo + (size_t)ar1 * 64 + g * 4 + kq * 16);
        }
    }

    f32x4 acc0[8], acc1[8];
    const f32x4 zero = {0.f, 0.f, 0.f, 0.f};
    #pragma unroll
    for (int t = 0; t < 8; ++t){ acc0[t] = zero; acc1[t] = zero; }

#define COMPUTE4(AM0, AM1, ADD_XLO)                                           \
    _Pragma("unroll")                                                         \
    for (int kk = 0; kk < 4; ++kk){                                           \
        _Pragma("unroll")                                                     \
        for (int t = 0; t < 8; ++t){                                          \
            bf16x8 bq = *(const bf16x8*)(&sB[kk][(t * 16 + l15) * 16 + gx4]); \
            acc0[t] = MFMA(AM0[kk], bq, acc0[t]);                             \
            acc1[t] = MFMA(AM1[kk], bq, acc1[t]);                             \
            if (ADD_XLO){                                                     \
                acc0[t] = MFMA(xl0[kk], bq, acc0[t]);                         \
                acc1[t] = MFMA(xl1[kk], bq, acc1[t]);                         \
            }                                                                 \
        }                                                                     \
    }

    __syncthreads();                                 // q1 staged + A-loads issued
    COMPUTE4(am0, am1, false);                       // hi, kt 0-3 (mean half)
    __syncthreads();
    stage4(Wpk, sB, wid, lane, 0, 1);                // quarter 2: hi, kt 4-7
    __syncthreads();
    COMPUTE4(ao0, ao1, (MODE == 0));                 // hi, kt 4-7 (own half, +xlo)
    __syncthreads();
    stage4(Wpk, sB, wid, lane, 1, 0);                // quarter 3: lo, kt 0-3
    __syncthreads();
    COMPUTE4(am0, am1, false);                       // lo, kt 0-3
    __syncthreads();
    stage4(Wpk, sB, wid, lane, 1, 1);                // quarter 4: lo, kt 4-7
    __syncthreads();
    COMPUTE4(ao0, ao1, false);                       // lo, kt 4-7
#undef COMPUTE4

    // ---- epilogue ----
    float bv[8];
    #pragma unroll
    for (int t = 0; t < 8; ++t) bv[t] = bias[t * 16 + l15];

    float fw[4]; float fb = 0.f;
    if (MODE == 1){
        #pragma unroll
        for (int t = 0; t < 4; ++t) fw[t] = fcW[t * 16 + l15];
        fb = fcb[0];
    }

    float pbs[8], pbq[8];
    #pragma unroll
    for (int t = 0; t < 8; ++t){ pbs[t] = 0.f; pbq[t] = 0.f; }

    #pragma unroll
    for (int m = 0; m < 2; ++m){
        #pragma unroll
        for (int j = 0; j < 4; ++j){
            int orow = rowb + m * 16 + 4 * g + j;
            bool valid = orow < N;
            float o[8]; float ss = 0.f;
            #pragma unroll
            for (int t = 0; t < 8; ++t){
                o[t] = (m == 0 ? acc0[t][j] : acc1[t][j]) + bv[t];
                ss += o[t] * o[t];
            }
            ss += __shfl_xor(ss, 1, 64);
            ss += __shfl_xor(ss, 2, 64);
            ss += __shfl_xor(ss, 4, 64);
            ss += __shfl_xor(ss, 8, 64);
            float inv = 1.0f / fmaxf(sqrtf(ss), 1e-12f);
            if (MODE == 0){
                #pragma unroll
                for (int t = 0; t < 8; ++t){
                    float v = fmaxf(o[t] * inv, 0.f);
                    float pv = __shfl_xor(v, 1, 64);          // partner col (uniform exec)
                    if (valid){
                        pbs[t] += v; pbq[t] += v * v;
                        if (!(lane & 1))
                            HbfOut[(size_t)orow * 64 + t * 8 + (l15 >> 1)] = packbf(v, pv);
                    }
                }
            } else {
                float p = 0.f;
                #pragma unroll
                for (int t = 0; t < 8; ++t){
                    float v = o[t] * inv;
                    if (valid) Emb[(size_t)orow * 128 + t * 16 + l15] = v;
                    if (t < 4) p += v * fw[t];
                }
                p += __shfl_xor(p, 1, 64);
                p += __shfl_xor(p, 2, 64);
                p += __shfl_xor(p, 4, 64);
                p += __shfl_xor(p, 8, 64);
                if (valid && l15 == 0) preds[orow] = p + fb;
            }
        }
    }

    if (MODE == 0){
        float* lsum = (float*)&sB[0][0];             // sB dead after last compute
        float* lsq  = lsum + 128;
        #pragma unroll
        for (int t = 0; t < 8; ++t){
            pbs[t] += __shfl_xor(pbs[t], 16, 64);
            pbs[t] += __shfl_xor(pbs[t], 32, 64);
            pbq[t] += __shfl_xor(pbq[t], 16, 64);
            pbq[t] += __shfl_xor(pbq[t], 32, 64);
        }
        __syncthreads();                             // all waves done reading sB
        if (threadIdx.x < 128){ lsum[threadIdx.x] = 0.f; lsq[threadIdx.x] = 0.f; }
        __syncthreads();
        if (lane < 16){
            #pragma unroll
            for (int t = 0; t < 8; ++t){
                atomicAdd(&lsum[t * 16 + lane], pbs[t]);
                atomicAdd(&lsq [t * 16 + lane], pbq[t]);
            }
        }
        __syncthreads();
        if (threadIdx.x < 128){
            atomicAdd(&bnsum[threadIdx.x],   lsum[threadIdx.x]);
            atomicAdd(&bnsumsq[threadIdx.x], lsq[threadIdx.x]);
        }
    }
}

// ---------- BN finalize + effective layer-2 bias (b2 + shift @ W2r) ----------
__global__ void k_bnfinal(const float* __restrict__ bnsum, const float* __restrict__ bnsumsq,
                          const float* __restrict__ gamma, const float* __restrict__ beta,
                          const float* __restrict__ W2r, const float* __restrict__ b2,
                          float* __restrict__ scale, float* __restrict__ shift,
                          float* __restrict__ bias2, int N){
    __shared__ float sh_l[128];
    int t = threadIdx.x;
    float invN = 1.0f / (float)N;
    float mu  = bnsum[t] * invN;
    float var = fmaxf(bnsumsq[t] * invN - mu * mu, 0.f);
    float istd = 1.0f / sqrtf(var + 1e-5f);
    float sc = gamma[t] * istd;
    float sf = beta[t] - mu * sc;
    scale[t] = sc; shift[t] = sf; sh_l[t] = sf;
    __syncthreads();
    float acc = b2[t];
    for (int k = 0; k < 128; ++k) acc += sh_l[k] * W2r[k * 128 + t];
    bias2[t] = acc;
}

__global__ void k_sent(float* __restrict__ preds, int N, float val){
    int i = blockIdx.x * 256 + threadIdx.x;
    if (i < N) preds[i] = val;
}

// ---------- launch ----------
extern "C" void kernel_launch(void* const* d_in, const int* in_sizes, int n_in,
                              void* d_out, int out_size, void* d_ws, size_t ws_size,
                              hipStream_t stream){
    const int N = in_sizes[0] / 128;
    const int E = in_sizes[1] / 2;

    const float* x    = (const float*)d_in[0];
    const int*   ei   = (const int*)d_in[1];
    const int*   src  = ei;
    const int*   dst  = ei + E;
    const float* W1l  = (const float*)d_in[2];
    const float* b1   = (const float*)d_in[3];
    const float* W1r  = (const float*)d_in[4];
    const float* gam  = (const float*)d_in[5];
    const float* bet  = (const float*)d_in[6];
    const float* W2l  = (const float*)d_in[7];
    const float* b2   = (const float*)d_in[8];
    const float* W2r  = (const float*)d_in[9];
    const float* fcW  = (const float*)d_in[10];
    const float* fcb  = (const float*)d_in[11];

    float* preds = (float*)d_out;                 // f32 [N]
    float* Emb   = preds + N;                     // f32 [N,128]
    uint32_t* EmbU = (uint32_t*)Emb;              // Xbf (1st half) + Mb (2nd half) scratch

    char* w = (char*)d_ws;
    auto carve = [&](size_t bytes){ char* p = w; w += (bytes + 255) & ~(size_t)255; return p; };
    int*   counts  = (int*)  carve((size_t)N * 8);   // counts[N] + cursor[N], one memset
    int*   cursor  = counts + N;
    int*   offs    = (int*)  carve((size_t)N * 4);
    int*   bsums   = (int*)  carve(256 * 4);
    float* bnsum   = (float*)carve(128 * 4);      // contiguous with bnsumsq (one memset)
    float* bnsumsq = (float*)carve(128 * 4);
    float* bnscale = (float*)carve(128 * 4);
    float* bnshift = (float*)carve(128 * 4);
    float* bias2   = (float*)carve(128 * 4);
    int*   ssrc    = (int*)  carve((size_t)E * 4);
    uint32_t* HbfXlo = (uint32_t*)carve((size_t)N * 256);  // Xlo then Hbf (overlay, alias-safe)
    uint16_t* Wpk1 = (uint16_t*)carve(131072);    // packed+swizzled [kt][hi/lo][512][8]
    uint16_t* Wpk2 = (uint16_t*)carve(131072);
    size_t need = (size_t)(w - (char*)d_ws);
    if (ws_size < need){
        float val = 1024.f + 4.f * (float)((ws_size >> 20) > 255 ? 255 : (ws_size >> 20));
        k_sent<<<(N + 255) / 256, 256, 0, stream>>>(preds, N, val);
        return;
    }

    hipMemsetAsync(counts, 0, (size_t)N * 8, stream);
    hipMemsetAsync(bnsum,  0, 1024, stream);

    const int eb = (E + 255) / 256;
    const int NB = (N + 2047) / 2048;
    const int ab = (N + 3) / 4;
    const int gb = (N + 127) / 128;
    const int xb = (N * 32 + 255) / 256;

    k_deg  <<<eb, 256, 0, stream>>>(dst, counts, E);
    k_scan1<<<NB, 256, 0, stream>>>(counts, bsums, N);
    k_scan2<<<1,    1, 0, stream>>>(bsums, NB);
    k_scan3<<<NB, 256, 0, stream>>>(counts, bsums, offs, N);
    k_fill <<<eb, 256, 0, stream>>>(src, dst, offs, cursor, ssrc, E);

    k_x2bf <<<xb, 256, 0, stream>>>(x, EmbU, HbfXlo, N);
    k_wprep<<<128, 256, 0, stream>>>(W1l, W1r, nullptr, Wpk1);

    // layer 1
    k_agg<0> <<<ab, 256, 0, stream>>>(EmbU, 128, offs, counts, ssrc,
                                      nullptr, nullptr, EmbU, N);
    k_gemm<0><<<gb, 256, 0, stream>>>(EmbU, HbfXlo, EmbU, (const uint32_t*)Wpk1, b1,
                                      HbfXlo, nullptr, bnsum, bnsumsq,
                                      nullptr, nullptr, nullptr, N);
    k_bnfinal<<<1, 128, 0, stream>>>(bnsum, bnsumsq, gam, bet, W2r, b2,
                                     bnscale, bnshift, bias2, N);
    k_wprep<<<128, 256, 0, stream>>>(W2l, W2r, bnscale, Wpk2);

    // layer 2
    k_agg<1> <<<ab, 256, 0, stream>>>(HbfXlo, 64, offs, counts, ssrc,
                                      bnscale, bnshift, EmbU, N);
    k_gemm<1><<<gb, 256, 0, stream>>>(HbfXlo, nullptr, EmbU, (const uint32_t*)Wpk2, bias2,
                                      nullptr, Emb, nullptr, nullptr,
                                      fcW, fcb, preds, N);
}

// Round 6
// 359.453 us; speedup vs baseline: 1.0749x; 1.0749x over previous
//
#include <hip/hip_runtime.h>
#include <hip/hip_bf16.h>
#include <stdint.h>

typedef __attribute__((ext_vector_type(8))) __bf16 bf16x8;
typedef __attribute__((ext_vector_type(4))) float  f32x4;

// ---------- bf16 helpers (bf16 pairs packed in uint32, little-endian) ----------
__device__ __forceinline__ float bflo(uint32_t p){ return __uint_as_float(p << 16); }
__device__ __forceinline__ float bfhi(uint32_t p){ return __uint_as_float(p & 0xffff0000u); }
__device__ __forceinline__ uint16_t f2bf(float f){
    uint32_t u = __float_as_uint(f);
    uint32_t r = (u + 0x7fffu + ((u >> 16) & 1u)) >> 16;   // RNE
    return (uint16_t)r;
}
__device__ __forceinline__ uint32_t packbf(float a, float b){
    return (uint32_t)f2bf(a) | ((uint32_t)f2bf(b) << 16);
}
__device__ __forceinline__ f32x4 MFMA(bf16x8 a, bf16x8 b, f32x4 c){
    return __builtin_amdgcn_mfma_f32_16x16x32_bf16(a, b, c, 0, 0, 0);
}

// Mean buffer lives in the SECOND HALF of each f32 Emb row (u32 units):
//   Mb(row) = Emb u32 [row*128 + 64, row*128 + 128).
// Xbf (layer-1 bf16 input) lives in the FIRST HALF: Emb u32 [row*128, row*128+64).

// ---------- CSR build ----------
__global__ void k_deg(const int* __restrict__ dst, int* __restrict__ counts, int E){
    int e = blockIdx.x * 256 + threadIdx.x;
    if (e < E) atomicAdd(&counts[dst[e]], 1);
}

__global__ void k_scan1(const int* __restrict__ counts, int* __restrict__ bsums, int N){
    __shared__ int lds[256];
    int t = threadIdx.x;
    int base = blockIdx.x * 2048 + t * 8;
    int s = 0;
    #pragma unroll
    for (int i = 0; i < 8; ++i){ int idx = base + i; s += (idx < N) ? counts[idx] : 0; }
    lds[t] = s; __syncthreads();
    for (int off = 128; off > 0; off >>= 1){
        if (t < off) lds[t] += lds[t + off];
        __syncthreads();
    }
    if (t == 0) bsums[blockIdx.x] = lds[0];
}

__global__ void k_scan2(int* bsums, int NB){
    int run = 0;
    for (int i = 0; i < NB; ++i){ int v = bsums[i]; bsums[i] = run; run += v; }
}

__global__ void k_scan3(const int* __restrict__ counts, const int* __restrict__ bsums,
                        int* __restrict__ offs, int N){
    __shared__ int lds[256];
    int t = threadIdx.x;
    int base = blockIdx.x * 2048 + t * 8;
    int local[8];
    int s = 0;
    #pragma unroll
    for (int i = 0; i < 8; ++i){
        int idx = base + i;
        int v = (idx < N) ? counts[idx] : 0;
        local[i] = v; s += v;
    }
    lds[t] = s; __syncthreads();
    for (int off = 1; off < 256; off <<= 1){
        int v = (t >= off) ? lds[t - off] : 0;
        __syncthreads();
        lds[t] += v;
        __syncthreads();
    }
    int run = bsums[blockIdx.x] + (lds[t] - s);
    #pragma unroll
    for (int i = 0; i < 8; ++i){
        int idx = base + i;
        if (idx < N){ offs[idx] = run; run += local[i]; }
    }
}

__global__ void k_fill(const int* __restrict__ src, const int* __restrict__ dst,
                       const int* __restrict__ offs, int* __restrict__ cursor,
                       int* __restrict__ ssrc, int E){
    int e = blockIdx.x * 256 + threadIdx.x;
    if (e < E){
        int d = dst[e];
        int p = atomicAdd(&cursor[d], 1);
        ssrc[offs[d] + p] = src[e];
    }
}

// ---------- x -> bf16 hi (into Emb first half) + bf16 lo residual ----------
__global__ __launch_bounds__(256) void k_x2bf(const float* __restrict__ X,
        uint32_t* __restrict__ XbfE, uint32_t* __restrict__ Xlo, int N){
    int i = blockIdx.x * 256 + threadIdx.x;          // 2-pair chunk, total N*32
    if (i >= N * 32) return;
    int row = i >> 5, l = i & 31;
    float4 v = *(const float4*)(X + (size_t)i * 4);
    uint16_t h0 = f2bf(v.x), h1 = f2bf(v.y), h2 = f2bf(v.z), h3 = f2bf(v.w);
    float r0 = v.x - __uint_as_float((uint32_t)h0 << 16);
    float r1 = v.y - __uint_as_float((uint32_t)h1 << 16);
    float r2 = v.z - __uint_as_float((uint32_t)h2 << 16);
    float r3 = v.w - __uint_as_float((uint32_t)h3 << 16);
    uint2 hi; hi.x = (uint32_t)h0 | ((uint32_t)h1 << 16);
    hi.y = (uint32_t)h2 | ((uint32_t)h3 << 16);
    uint2 lo; lo.x = packbf(r0, r1); lo.y = packbf(r2, r3);
    *(uint2*)(XbfE + (size_t)row * 128 + l * 2) = hi;
    *(uint2*)(Xlo  + (size_t)row * 64  + l * 2) = lo;
}

// ---------- weight prep: packed + bank-swizzled layout for LDS staging ----------
// Wpk u16 layout: [kt(8)][sel(2: hi,lo)][slot(512)][e(8)]
//   slot(c,g) = 4*c + (g ^ ((c>>1)&3))   (bank swizzle: octet of lanes -> 8 distinct
//   16B slots -> all 32 banks once per octet on ds_read_b128)
// source: k<128 -> Wl[k][c], k>=128 -> scale*Wr[k-128][c];  k = kt*32 + g*8 + e
__global__ void k_wprep(const float* __restrict__ Wl, const float* __restrict__ Wr,
                        const float* __restrict__ scale,
                        uint16_t* __restrict__ Wpk){
    int idx = blockIdx.x * 256 + threadIdx.x;        // [0, 32768) = c*256 + k
    int c = idx >> 8, k = idx & 255;
    float v;
    if (k < 128){
        v = Wl[k * 128 + c];
    } else {
        v = Wr[(k - 128) * 128 + c];
        if (scale) v *= scale[k - 128];
    }
    uint16_t h = f2bf(v);
    float r = v - __uint_as_float((uint32_t)h << 16);
    int kt = k >> 5, kk = k & 31;
    int g = kk >> 3, e = kk & 7;
    int slot = (c << 2) | (g ^ ((c >> 1) & 3));
    size_t base = (size_t)kt * 8192 + (size_t)slot * 8 + e;
    Wpk[base]        = h;
    Wpk[base + 4096] = f2bf(r);
}

// ---------- neighbor mean: one wave per node; 4 rows per wave-load (uint4) --------
// 16-lane group q loads full 256B row of neighbor (j+q); 8 rows in flight per iter.
// Cross-group shfl reduce at end. MODE 1 folds BN (shift only when cnt>0).
template<int MODE>
__global__ __launch_bounds__(256) void k_agg(
        const uint32_t* __restrict__ Src, int sstr,
        const int* __restrict__ offs, const int* __restrict__ counts,
        const int* __restrict__ ssrc,
        const float* __restrict__ bnscale, const float* __restrict__ bnshift,
        uint32_t* __restrict__ MbBase, int N){
    const int lane = threadIdx.x & 63;
    const int l15  = lane & 15;
    const int q    = lane >> 4;
    int node = blockIdx.x * 4 + (threadIdx.x >> 6);
    if (node >= N) return;
    int cnt = counts[node];
    if (cnt < 0) cnt = 0;
    int off = offs[node];
    const uint32_t* srcb = Src + l15 * 4;
    float a[8];
    #pragma unroll
    for (int i = 0; i < 8; ++i) a[i] = 0.f;

    int j = 0;
    for (; j + 8 <= cnt; j += 8){                     // 8 rows in flight (2 x 4 groups)
        int s0 = ssrc[off + j + q];
        int s1 = ssrc[off + j + 4 + q];
        s0 = (s0 < 0) ? 0 : ((s0 >= N) ? (N - 1) : s0);
        s1 = (s1 < 0) ? 0 : ((s1 >= N) ? (N - 1) : s1);
        uint4 v0 = *(const uint4*)(srcb + (size_t)s0 * sstr);
        uint4 v1 = *(const uint4*)(srcb + (size_t)s1 * sstr);
        a[0] += bflo(v0.x) + bflo(v1.x); a[1] += bfhi(v0.x) + bfhi(v1.x);
        a[2] += bflo(v0.y) + bflo(v1.y); a[3] += bfhi(v0.y) + bfhi(v1.y);
        a[4] += bflo(v0.z) + bflo(v1.z); a[5] += bfhi(v0.z) + bfhi(v1.z);
        a[6] += bflo(v0.w) + bflo(v1.w); a[7] += bfhi(v0.w) + bfhi(v1.w);
    }
    int rem = cnt - j;
    if (rem > 0){
        if (q < rem){
            int s0 = ssrc[off + j + q];
            s0 = (s0 < 0) ? 0 : ((s0 >= N) ? (N - 1) : s0);
            uint4 v0 = *(const uint4*)(srcb + (size_t)s0 * sstr);
            a[0] += bflo(v0.x); a[1] += bfhi(v0.x);
            a[2] += bflo(v0.y); a[3] += bfhi(v0.y);
            a[4] += bflo(v0.z); a[5] += bfhi(v0.z);
            a[6] += bflo(v0.w); a[7] += bfhi(v0.w);
        }
        if (rem > 4 && q < rem - 4){
            int s1 = ssrc[off + j + 4 + q];
            s1 = (s1 < 0) ? 0 : ((s1 >= N) ? (N - 1) : s1);
            uint4 v1 = *(const uint4*)(srcb + (size_t)s1 * sstr);
            a[0] += bflo(v1.x); a[1] += bfhi(v1.x);
            a[2] += bflo(v1.y); a[3] += bfhi(v1.y);
            a[4] += bflo(v1.z); a[5] += bfhi(v1.z);
            a[6] += bflo(v1.w); a[7] += bfhi(v1.w);
        }
    }

    // reduce across the 4 row-groups (lanes l15, l15+16, l15+32, l15+48)
    #pragma unroll
    for (int i = 0; i < 8; ++i){
        a[i] += __shfl_xor(a[i], 16, 64);
        a[i] += __shfl_xor(a[i], 32, 64);
    }
    float inv = 1.0f / fmaxf((float)cnt, 1.0f);
    #pragma unroll
    for (int i = 0; i < 8; ++i) a[i] *= inv;

    if (MODE == 1){
        if (cnt > 0){                                  // ref: zero-degree mean == 0
            int c0 = l15 * 8;
            float4 sc0 = *(const float4*)(bnscale + c0);
            float4 sc1 = *(const float4*)(bnscale + c0 + 4);
            float4 sh0 = *(const float4*)(bnshift + c0);
            float4 sh1 = *(const float4*)(bnshift + c0 + 4);
            a[0] = a[0] * sc0.x + sh0.x; a[1] = a[1] * sc0.y + sh0.y;
            a[2] = a[2] * sc0.z + sh0.z; a[3] = a[3] * sc0.w + sh0.w;
            a[4] = a[4] * sc1.x + sh1.x; a[5] = a[5] * sc1.y + sh1.y;
            a[6] = a[6] * sc1.z + sh1.z; a[7] = a[7] * sc1.w + sh1.w;
        } else {
            #pragma unroll
            for (int i = 0; i < 8; ++i) a[i] = 0.f;
        }
    }

    if (q == 0){
        uint4 o;
        o.x = packbf(a[0], a[1]); o.y = packbf(a[2], a[3]);
        o.z = packbf(a[4], a[5]); o.w = packbf(a[6], a[7]);
        *(uint4*)(MbBase + (size_t)node * 128 + 64 + l15 * 4) = o;
    }
}

// stage one quarter (32 KiB: 4 kt of one sel) of B into sB.
// LDS dest is wave-uniform base (+ lane*16 by HW); global src is per-lane.
__device__ __forceinline__ void stage4(const uint32_t* Wpk, uint32_t (*sB)[2048],
                                       int wid, int lane, int sel, int half){
    #pragma unroll
    for (int i = 0; i < 8; ++i){
        int ch = wid * 8 + i;                        // 32 chunks of 1 KiB
        int ktv = ch >> 3, part = ch & 7;
        __builtin_amdgcn_global_load_lds(
            Wpk + (size_t)(half * 4 + ktv) * 4096 + sel * 2048 + part * 256 + lane * 4,
            &sB[ktv][part * 256], 16, 0, 0);
    }
}

// ---------- MFMA dual-GEMM (K=256 = [mean|own]) + L2-normalize ----------
// Wave owns 32 rows (2 m-tiles), all 128 cols (8 n-tiles).
// All A fragments hoisted to registers up front.  B staged in FOUR 32 KiB
// quarters (hi/lo x K-halves) through one 32 KiB LDS buffer.
// launch_bounds(256,2): R5 showed (256,4) caps VGPR at 64 -> massive scratch
// spills (FETCH+WRITE 66->168 MB, dur 56->97us). (256,2) = no-spill regime
// (~108-130 VGPR); HW residency then 3-4 blocks/CU via 32 KiB LDS.
// A frag:  lane holds row (lane&15), k = 32*kt + 8*(lane>>4) + e  (contiguous 16B)
// B frag:  swizzled slot; gx = g ^ ((l15>>1)&3)   (conflict-free ds_read_b128)
// C/D:     col = lane&15, row = 4*(lane>>4) + reg   (m89-verified)
// MODE 0: own=Xbf (+Xlo correction on hi); out=relu(norm(.)); Hbf store + BN sums.
// MODE 1: own=Hbf (BN folded into Wpk/bias); out=norm(.); Emb f32 + preds.
template<int MODE>
__global__ __launch_bounds__(256, 2) void k_gemm(
        const uint32_t* Own,                 // MODE0: Xbf in Emb rows (stride 128); MODE1: Hbf (stride 64)
        const uint32_t* OwnLo,               // MODE0 only: Xlo (stride 64; aliases HbfOut)
        const uint32_t* Mb,                  // bf16 means at Emb rows' 2nd half
        const uint32_t* __restrict__ Wpk,    // packed+swizzled [kt][hi/lo][512 slots][8] u16
        const float* __restrict__ bias,      // [128] effective bias
        uint32_t* HbfOut,                    // MODE0 out (aliases OwnLo; alias-safe per-wave)
        float* Emb,                          // MODE1 out (aliases Mb rows; reads precede writes)
        float* __restrict__ bnsum, float* __restrict__ bnsumsq,             // MODE0
        const float* __restrict__ fcW, const float* __restrict__ fcb,       // MODE1
        float* __restrict__ preds, int N){
    __shared__ uint32_t __align__(16) sB[4][2048];   // 32 KiB; reused 4x; aliased by lsum/lsq at end
    const int lane = threadIdx.x & 63;
    const int wid  = threadIdx.x >> 6;
    const int l15  = lane & 15;
    const int g    = lane >> 4;
    const int gx4  = (g ^ ((l15 >> 1) & 3)) * 4;     // swizzled 16B sub-slot (u32 units)
    const int ostr = (MODE == 0) ? 128 : 64;
    const int rowb = blockIdx.x * 128 + wid * 32;    // may be >= N: wave stays for staging

    stage4(Wpk, sB, wid, lane, 0, 0);                // quarter 1: hi, kt 0-3

    int ar0 = rowb + l15;      if (ar0 >= N) ar0 = N - 1;   // clamped dup rows: discarded
    int ar1 = rowb + 16 + l15; if (ar1 >= N) ar1 = N - 1;

    const uint32_t* mp0 = Mb  + (size_t)ar0 * 128 + 64 + g * 4;
    const uint32_t* mp1 = Mb  + (size_t)ar1 * 128 + 64 + g * 4;
    const uint32_t* op0 = Own + (size_t)ar0 * ostr + g * 4;
    const uint32_t* op1 = Own + (size_t)ar1 * ostr + g * 4;

    // hoist ALL A fragments into registers (independent loads, overlap staging)
    bf16x8 am0[4], am1[4], ao0[4], ao1[4];
    #pragma unroll
    for (int kq = 0; kq < 4; ++kq){
        am0[kq] = *(const bf16x8*)(mp0 + kq * 16);
        am1[kq] = *(const bf16x8*)(mp1 + kq * 16);
        ao0[kq] = *(const bf16x8*)(op0 + kq * 16);
        ao1[kq] = *(const bf16x8*)(op1 + kq * 16);
    }
    bf16x8 xl0[4], xl1[4];
    if (MODE == 0){
        #pragma unroll
        for (int kq = 0; kq < 4; ++kq){
            xl0[kq] = *(const bf16x8*)(OwnLo + (size_t)ar0 * 64 + g * 4 + kq * 16);
            xl1[kq] = *(const bf16x8*)(OwnLo + (size_t)ar1 * 64 + g * 4 + kq * 16);
        }
    }

    f32x4 acc0[8], acc1[8];
    const f32x4 zero = {0.f, 0.f, 0.f, 0.f};
    #pragma unroll
    for (int t = 0; t < 8; ++t){ acc0[t] = zero; acc1[t] = zero; }

#define COMPUTE4(AM0, AM1, ADD_XLO)                                           \
    _Pragma("unroll")                                                         \
    for (int kk = 0; kk < 4; ++kk){                                           \
        _Pragma("unroll")                                                     \
        for (int t = 0; t < 8; ++t){                                          \
            bf16x8 bq = *(const bf16x8*)(&sB[kk][(t * 16 + l15) * 16 + gx4]); \
            acc0[t] = MFMA(AM0[kk], bq, acc0[t]);                             \
            acc1[t] = MFMA(AM1[kk], bq, acc1[t]);                             \
            if (ADD_XLO){                                                     \
                acc0[t] = MFMA(xl0[kk], bq, acc0[t]);                         \
                acc1[t] = MFMA(xl1[kk], bq, acc1[t]);                         \
            }                                                                 \
        }                                                                     \
    }

    __syncthreads();                                 // q1 staged + A-loads issued
    COMPUTE4(am0, am1, false);                       // hi, kt 0-3 (mean half)
    __syncthreads();
    stage4(Wpk, sB, wid, lane, 0, 1);                // quarter 2: hi, kt 4-7
    __syncthreads();
    COMPUTE4(ao0, ao1, (MODE == 0));                 // hi, kt 4-7 (own half, +xlo)
    __syncthreads();
    stage4(Wpk, sB, wid, lane, 1, 0);                // quarter 3: lo, kt 0-3
    __syncthreads();
    COMPUTE4(am0, am1, false);                       // lo, kt 0-3
    __syncthreads();
    stage4(Wpk, sB, wid, lane, 1, 1);                // quarter 4: lo, kt 4-7
    __syncthreads();
    COMPUTE4(ao0, ao1, false);                       // lo, kt 4-7
#undef COMPUTE4

    // ---- epilogue ----
    float bv[8];
    #pragma unroll
    for (int t = 0; t < 8; ++t) bv[t] = bias[t * 16 + l15];

    float fw[4]; float fb = 0.f;
    if (MODE == 1){
        #pragma unroll
        for (int t = 0; t < 4; ++t) fw[t] = fcW[t * 16 + l15];
        fb = fcb[0];
    }

    float pbs[8], pbq[8];
    #pragma unroll
    for (int t = 0; t < 8; ++t){ pbs[t] = 0.f; pbq[t] = 0.f; }

    #pragma unroll
    for (int m = 0; m < 2; ++m){
        #pragma unroll
        for (int j = 0; j < 4; ++j){
            int orow = rowb + m * 16 + 4 * g + j;
            bool valid = orow < N;
            float o[8]; float ss = 0.f;
            #pragma unroll
            for (int t = 0; t < 8; ++t){
                o[t] = (m == 0 ? acc0[t][j] : acc1[t][j]) + bv[t];
                ss += o[t] * o[t];
            }
            ss += __shfl_xor(ss, 1, 64);
            ss += __shfl_xor(ss, 2, 64);
            ss += __shfl_xor(ss, 4, 64);
            ss += __shfl_xor(ss, 8, 64);
            float inv = 1.0f / fmaxf(sqrtf(ss), 1e-12f);
            if (MODE == 0){
                #pragma unroll
                for (int t = 0; t < 8; ++t){
                    float v = fmaxf(o[t] * inv, 0.f);
                    float pv = __shfl_xor(v, 1, 64);          // partner col (uniform exec)
                    if (valid){
                        pbs[t] += v; pbq[t] += v * v;
                        if (!(lane & 1))
                            HbfOut[(size_t)orow * 64 + t * 8 + (l15 >> 1)] = packbf(v, pv);
                    }
                }
            } else {
                float p = 0.f;
                #pragma unroll
                for (int t = 0; t < 8; ++t){
                    float v = o[t] * inv;
                    if (valid) Emb[(size_t)orow * 128 + t * 16 + l15] = v;
                    if (t < 4) p += v * fw[t];
                }
                p += __shfl_xor(p, 1, 64);
                p += __shfl_xor(p, 2, 64);
                p += __shfl_xor(p, 4, 64);
                p += __shfl_xor(p, 8, 64);
                if (valid && l15 == 0) preds[orow] = p + fb;
            }
        }
    }

    if (MODE == 0){
        float* lsum = (float*)&sB[0][0];             // sB dead after last compute
        float* lsq  = lsum + 128;
        #pragma unroll
        for (int t = 0; t < 8; ++t){
            pbs[t] += __shfl_xor(pbs[t], 16, 64);
            pbs[t] += __shfl_xor(pbs[t], 32, 64);
            pbq[t] += __shfl_xor(pbq[t], 16, 64);
            pbq[t] += __shfl_xor(pbq[t], 32, 64);
        }
        __syncthreads();                             // all waves done reading sB
        if (threadIdx.x < 128){ lsum[threadIdx.x] = 0.f; lsq[threadIdx.x] = 0.f; }
        __syncthreads();
        if (lane < 16){
            #pragma unroll
            for (int t = 0; t < 8; ++t){
                atomicAdd(&lsum[t * 16 + lane], pbs[t]);
                atomicAdd(&lsq [t * 16 + lane], pbq[t]);
            }
        }
        __syncthreads();
        if (threadIdx.x < 128){
            atomicAdd(&bnsum[threadIdx.x],   lsum[threadIdx.x]);
            atomicAdd(&bnsumsq[threadIdx.x], lsq[threadIdx.x]);
        }
    }
}

// ---------- BN finalize + effective layer-2 bias (b2 + shift @ W2r) ----------
__global__ void k_bnfinal(const float* __restrict__ bnsum, const float* __restrict__ bnsumsq,
                          const float* __restrict__ gamma, const float* __restrict__ beta,
                          const float* __restrict__ W2r, const float* __restrict__ b2,
                          float* __restrict__ scale, float* __restrict__ shift,
                          float* __restrict__ bias2, int N){
    __shared__ float sh_l[128];
    int t = threadIdx.x;
    float invN = 1.0f / (float)N;
    float mu  = bnsum[t] * invN;
    float var = fmaxf(bnsumsq[t] * invN - mu * mu, 0.f);
    float istd = 1.0f / sqrtf(var + 1e-5f);
    float sc = gamma[t] * istd;
    float sf = beta[t] - mu * sc;
    scale[t] = sc; shift[t] = sf; sh_l[t] = sf;
    __syncthreads();
    float acc = b2[t];
    for (int k = 0; k < 128; ++k) acc += sh_l[k] * W2r[k * 128 + t];
    bias2[t] = acc;
}

__global__ void k_sent(float* __restrict__ preds, int N, float val){
    int i = blockIdx.x * 256 + threadIdx.x;
    if (i < N) preds[i] = val;
}

// ---------- launch ----------
extern "C" void kernel_launch(void* const* d_in, const int* in_sizes, int n_in,
                              void* d_out, int out_size, void* d_ws, size_t ws_size,
                              hipStream_t stream){
    const int N = in_sizes[0] / 128;
    const int E = in_sizes[1] / 2;

    const float* x    = (const float*)d_in[0];
    const int*   ei   = (const int*)d_in[1];
    const int*   src  = ei;
    const int*   dst  = ei + E;
    const float* W1l  = (const float*)d_in[2];
    const float* b1   = (const float*)d_in[3];
    const float* W1r  = (const float*)d_in[4];
    const float* gam  = (const float*)d_in[5];
    const float* bet  = (const float*)d_in[6];
    const float* W2l  = (const float*)d_in[7];
    const float* b2   = (const float*)d_in[8];
    const float* W2r  = (const float*)d_in[9];
    const float* fcW  = (const float*)d_in[10];
    const float* fcb  = (const float*)d_in[11];

    float* preds = (float*)d_out;                 // f32 [N]
    float* Emb   = preds + N;                     // f32 [N,128]
    uint32_t* EmbU = (uint32_t*)Emb;              // Xbf (1st half) + Mb (2nd half) scratch

    char* w = (char*)d_ws;
    auto carve = [&](size_t bytes){ char* p = w; w += (bytes + 255) & ~(size_t)255; return p; };
    int*   counts  = (int*)  carve((size_t)N * 8);   // counts[N] + cursor[N], one memset
    int*   cursor  = counts + N;
    int*   offs    = (int*)  carve((size_t)N * 4);
    int*   bsums   = (int*)  carve(256 * 4);
    float* bnsum   = (float*)carve(128 * 4);      // contiguous with bnsumsq (one memset)
    float* bnsumsq = (float*)carve(128 * 4);
    float* bnscale = (float*)carve(128 * 4);
    float* bnshift = (float*)carve(128 * 4);
    float* bias2   = (float*)carve(128 * 4);
    int*   ssrc    = (int*)  carve((size_t)E * 4);
    uint32_t* HbfXlo = (uint32_t*)carve((size_t)N * 256);  // Xlo then Hbf (overlay, alias-safe)
    uint16_t* Wpk1 = (uint16_t*)carve(131072);    // packed+swizzled [kt][hi/lo][512][8]
    uint16_t* Wpk2 = (uint16_t*)carve(131072);
    size_t need = (size_t)(w - (char*)d_ws);
    if (ws_size < need){
        float val = 1024.f + 4.f * (float)((ws_size >> 20) > 255 ? 255 : (ws_size >> 20));
        k_sent<<<(N + 255) / 256, 256, 0, stream>>>(preds, N, val);
        return;
    }

    hipMemsetAsync(counts, 0, (size_t)N * 8, stream);
    hipMemsetAsync(bnsum,  0, 1024, stream);

    const int eb = (E + 255) / 256;
    const int NB = (N + 2047) / 2048;
    const int ab = (N + 3) / 4;
    const int gb = (N + 127) / 128;
    const int xb = (N * 32 + 255) / 256;

    k_deg  <<<eb, 256, 0, stream>>>(dst, counts, E);
    k_scan1<<<NB, 256, 0, stream>>>(counts, bsums, N);
    k_scan2<<<1,    1, 0, stream>>>(bsums, NB);
    k_scan3<<<NB, 256, 0, stream>>>(counts, bsums, offs, N);
    k_fill <<<eb, 256, 0, stream>>>(src, dst, offs, cursor, ssrc, E);

    k_x2bf <<<xb, 256, 0, stream>>>(x, EmbU, HbfXlo, N);
    k_wprep<<<128, 256, 0, stream>>>(W1l, W1r, nullptr, Wpk1);

    // layer 1
    k_agg<0> <<<ab, 256, 0, stream>>>(EmbU, 128, offs, counts, ssrc,
                                      nullptr, nullptr, EmbU, N);
    k_gemm<0><<<gb, 256, 0, stream>>>(EmbU, HbfXlo, EmbU, (const uint32_t*)Wpk1, b1,
                                      HbfXlo, nullptr, bnsum, bnsumsq,
                                      nullptr, nullptr, nullptr, N);
    k_bnfinal<<<1, 128, 0, stream>>>(bnsum, bnsumsq, gam, bet, W2r, b2,
                                     bnscale, bnshift, bias2, N);
    k_wprep<<<128, 256, 0, stream>>>(W2l, W2r, bnscale, Wpk2);

    // layer 2
    k_agg<1> <<<ab, 256, 0, stream>>>(HbfXlo, 64, offs, counts, ssrc,
                                      bnscale, bnshift, EmbU, N);
    k_gemm<1><<<gb, 256, 0, stream>>>(HbfXlo, nullptr, EmbU, (const uint32_t*)Wpk2, bias2,
                                      nullptr, Emb, nullptr, nullptr,
                                      fcW, fcb, preds, N);
}

// Round 7
// 356.508 us; speedup vs baseline: 1.0837x; 1.0083x over previous
//
#include <hip/hip_runtime.h>
#include <hip/hip_bf16.h>
#include <stdint.h>

typedef __attribute__((ext_vector_type(8))) __bf16 bf16x8;
typedef __attribute__((ext_vector_type(4))) float  f32x4;

// ---------- bf16 helpers (bf16 pairs packed in uint32, little-endian) ----------
__device__ __forceinline__ float bflo(uint32_t p){ return __uint_as_float(p << 16); }
__device__ __forceinline__ float bfhi(uint32_t p){ return __uint_as_float(p & 0xffff0000u); }
__device__ __forceinline__ uint16_t f2bf(float f){
    uint32_t u = __float_as_uint(f);
    uint32_t r = (u + 0x7fffu + ((u >> 16) & 1u)) >> 16;   // RNE
    return (uint16_t)r;
}
__device__ __forceinline__ uint32_t packbf(float a, float b){
    return (uint32_t)f2bf(a) | ((uint32_t)f2bf(b) << 16);
}
__device__ __forceinline__ f32x4 MFMA(bf16x8 a, bf16x8 b, f32x4 c){
    return __builtin_amdgcn_mfma_f32_16x16x32_bf16(a, b, c, 0, 0, 0);
}

// Mean buffer lives in the SECOND HALF of each f32 Emb row (u32 units):
//   Mb(row) = Emb u32 [row*128 + 64, row*128 + 128).
// Xbf (layer-1 bf16 input) lives in the FIRST HALF: Emb u32 [row*128, row*128+64).

// ---------- CSR build ----------
__global__ void k_deg(const int* __restrict__ dst, int* __restrict__ counts, int E){
    int e = blockIdx.x * 256 + threadIdx.x;
    if (e < E) atomicAdd(&counts[dst[e]], 1);
}

__global__ void k_scan1(const int* __restrict__ counts, int* __restrict__ bsums, int N){
    __shared__ int lds[256];
    int t = threadIdx.x;
    int base = blockIdx.x * 2048 + t * 8;
    int s = 0;
    #pragma unroll
    for (int i = 0; i < 8; ++i){ int idx = base + i; s += (idx < N) ? counts[idx] : 0; }
    lds[t] = s; __syncthreads();
    for (int off = 128; off > 0; off >>= 1){
        if (t < off) lds[t] += lds[t + off];
        __syncthreads();
    }
    if (t == 0) bsums[blockIdx.x] = lds[0];
}

__global__ void k_scan2(int* bsums, int NB){
    int run = 0;
    for (int i = 0; i < NB; ++i){ int v = bsums[i]; bsums[i] = run; run += v; }
}

__global__ void k_scan3(const int* __restrict__ counts, const int* __restrict__ bsums,
                        int* __restrict__ offs, int N){
    __shared__ int lds[256];
    int t = threadIdx.x;
    int base = blockIdx.x * 2048 + t * 8;
    int local[8];
    int s = 0;
    #pragma unroll
    for (int i = 0; i < 8; ++i){
        int idx = base + i;
        int v = (idx < N) ? counts[idx] : 0;
        local[i] = v; s += v;
    }
    lds[t] = s; __syncthreads();
    for (int off = 1; off < 256; off <<= 1){
        int v = (t >= off) ? lds[t - off] : 0;
        __syncthreads();
        lds[t] += v;
        __syncthreads();
    }
    int run = bsums[blockIdx.x] + (lds[t] - s);
    #pragma unroll
    for (int i = 0; i < 8; ++i){
        int idx = base + i;
        if (idx < N){ offs[idx] = run; run += local[i]; }
    }
}

__global__ void k_fill(const int* __restrict__ src, const int* __restrict__ dst,
                       const int* __restrict__ offs, int* __restrict__ cursor,
                       int* __restrict__ ssrc, int E){
    int e = blockIdx.x * 256 + threadIdx.x;
    if (e < E){
        int d = dst[e];
        int p = atomicAdd(&cursor[d], 1);
        ssrc[offs[d] + p] = src[e];
    }
}

// ---------- x -> bf16 hi (into Emb first half) + bf16 lo residual ----------
__global__ __launch_bounds__(256) void k_x2bf(const float* __restrict__ X,
        uint32_t* __restrict__ XbfE, uint32_t* __restrict__ Xlo, int N){
    int i = blockIdx.x * 256 + threadIdx.x;          // 2-pair chunk, total N*32
    if (i >= N * 32) return;
    int row = i >> 5, l = i & 31;
    float4 v = *(const float4*)(X + (size_t)i * 4);
    uint16_t h0 = f2bf(v.x), h1 = f2bf(v.y), h2 = f2bf(v.z), h3 = f2bf(v.w);
    float r0 = v.x - __uint_as_float((uint32_t)h0 << 16);
    float r1 = v.y - __uint_as_float((uint32_t)h1 << 16);
    float r2 = v.z - __uint_as_float((uint32_t)h2 << 16);
    float r3 = v.w - __uint_as_float((uint32_t)h3 << 16);
    uint2 hi; hi.x = (uint32_t)h0 | ((uint32_t)h1 << 16);
    hi.y = (uint32_t)h2 | ((uint32_t)h3 << 16);
    uint2 lo; lo.x = packbf(r0, r1); lo.y = packbf(r2, r3);
    *(uint2*)(XbfE + (size_t)row * 128 + l * 2) = hi;
    *(uint2*)(Xlo  + (size_t)row * 64  + l * 2) = lo;
}

// ---------- weight prep: packed + bank-swizzled layout for LDS staging ----------
// Wpk u16 layout: [kt(8)][sel(2: hi,lo)][slot(512)][e(8)]
//   slot(c,g) = 4*c + (g ^ ((c>>1)&3))   (bank swizzle: octet of lanes -> 8 distinct
//   16B slots -> all 32 banks once per octet on ds_read_b128)
// source: k<128 -> Wl[k][c], k>=128 -> scale*Wr[k-128][c];  k = kt*32 + g*8 + e
__global__ void k_wprep(const float* __restrict__ Wl, const float* __restrict__ Wr,
                        const float* __restrict__ scale,
                        uint16_t* __restrict__ Wpk){
    int idx = blockIdx.x * 256 + threadIdx.x;        // [0, 32768) = c*256 + k
    int c = idx >> 8, k = idx & 255;
    float v;
    if (k < 128){
        v = Wl[k * 128 + c];
    } else {
        v = Wr[(k - 128) * 128 + c];
        if (scale) v *= scale[k - 128];
    }
    uint16_t h = f2bf(v);
    float r = v - __uint_as_float((uint32_t)h << 16);
    int kt = k >> 5, kk = k & 31;
    int g = kk >> 3, e = kk & 7;
    int slot = (c << 2) | (g ^ ((c >> 1) & 3));
    size_t base = (size_t)kt * 8192 + (size_t)slot * 8 + e;
    Wpk[base]        = h;
    Wpk[base + 4096] = f2bf(r);
}

// ---------- neighbor mean: one wave per node; 4 rows per wave-load (uint4) --------
// 16-lane group q loads full 256B row of neighbor (j+q); 8 rows in flight per iter.
// Cross-group shfl reduce at end. MODE 1 folds BN (shift only when cnt>0).
template<int MODE>
__global__ __launch_bounds__(256) void k_agg(
        const uint32_t* __restrict__ Src, int sstr,
        const int* __restrict__ offs, const int* __restrict__ counts,
        const int* __restrict__ ssrc,
        const float* __restrict__ bnscale, const float* __restrict__ bnshift,
        uint32_t* __restrict__ MbBase, int N){
    const int lane = threadIdx.x & 63;
    const int l15  = lane & 15;
    const int q    = lane >> 4;
    int node = blockIdx.x * 4 + (threadIdx.x >> 6);
    if (node >= N) return;
    int cnt = counts[node];
    if (cnt < 0) cnt = 0;
    int off = offs[node];
    const uint32_t* srcb = Src + l15 * 4;
    float a[8];
    #pragma unroll
    for (int i = 0; i < 8; ++i) a[i] = 0.f;

    int j = 0;
    for (; j + 8 <= cnt; j += 8){                     // 8 rows in flight (2 x 4 groups)
        int s0 = ssrc[off + j + q];
        int s1 = ssrc[off + j + 4 + q];
        s0 = (s0 < 0) ? 0 : ((s0 >= N) ? (N - 1) : s0);
        s1 = (s1 < 0) ? 0 : ((s1 >= N) ? (N - 1) : s1);
        uint4 v0 = *(const uint4*)(srcb + (size_t)s0 * sstr);
        uint4 v1 = *(const uint4*)(srcb + (size_t)s1 * sstr);
        a[0] += bflo(v0.x) + bflo(v1.x); a[1] += bfhi(v0.x) + bfhi(v1.x);
        a[2] += bflo(v0.y) + bflo(v1.y); a[3] += bfhi(v0.y) + bfhi(v1.y);
        a[4] += bflo(v0.z) + bflo(v1.z); a[5] += bfhi(v0.z) + bfhi(v1.z);
        a[6] += bflo(v0.w) + bflo(v1.w); a[7] += bfhi(v0.w) + bfhi(v1.w);
    }
    int rem = cnt - j;
    if (rem > 0){
        if (q < rem){
            int s0 = ssrc[off + j + q];
            s0 = (s0 < 0) ? 0 : ((s0 >= N) ? (N - 1) : s0);
            uint4 v0 = *(const uint4*)(srcb + (size_t)s0 * sstr);
            a[0] += bflo(v0.x); a[1] += bfhi(v0.x);
            a[2] += bflo(v0.y); a[3] += bfhi(v0.y);
            a[4] += bflo(v0.z); a[5] += bfhi(v0.z);
            a[6] += bflo(v0.w); a[7] += bfhi(v0.w);
        }
        if (rem > 4 && q < rem - 4){
            int s1 = ssrc[off + j + 4 + q];
            s1 = (s1 < 0) ? 0 : ((s1 >= N) ? (N - 1) : s1);
            uint4 v1 = *(const uint4*)(srcb + (size_t)s1 * sstr);
            a[0] += bflo(v1.x); a[1] += bfhi(v1.x);
            a[2] += bflo(v1.y); a[3] += bfhi(v1.y);
            a[4] += bflo(v1.z); a[5] += bfhi(v1.z);
            a[6] += bflo(v1.w); a[7] += bfhi(v1.w);
        }
    }

    // reduce across the 4 row-groups (lanes l15, l15+16, l15+32, l15+48)
    #pragma unroll
    for (int i = 0; i < 8; ++i){
        a[i] += __shfl_xor(a[i], 16, 64);
        a[i] += __shfl_xor(a[i], 32, 64);
    }
    float inv = 1.0f / fmaxf((float)cnt, 1.0f);
    #pragma unroll
    for (int i = 0; i < 8; ++i) a[i] *= inv;

    if (MODE == 1){
        if (cnt > 0){                                  // ref: zero-degree mean == 0
            int c0 = l15 * 8;
            float4 sc0 = *(const float4*)(bnscale + c0);
            float4 sc1 = *(const float4*)(bnscale + c0 + 4);
            float4 sh0 = *(const float4*)(bnshift + c0);
            float4 sh1 = *(const float4*)(bnshift + c0 + 4);
            a[0] = a[0] * sc0.x + sh0.x; a[1] = a[1] * sc0.y + sh0.y;
            a[2] = a[2] * sc0.z + sh0.z; a[3] = a[3] * sc0.w + sh0.w;
            a[4] = a[4] * sc1.x + sh1.x; a[5] = a[5] * sc1.y + sh1.y;
            a[6] = a[6] * sc1.z + sh1.z; a[7] = a[7] * sc1.w + sh1.w;
        } else {
            #pragma unroll
            for (int i = 0; i < 8; ++i) a[i] = 0.f;
        }
    }

    if (q == 0){
        uint4 o;
        o.x = packbf(a[0], a[1]); o.y = packbf(a[2], a[3]);
        o.z = packbf(a[4], a[5]); o.w = packbf(a[6], a[7]);
        *(uint4*)(MbBase + (size_t)node * 128 + 64 + l15 * 4) = o;
    }
}

// stage one quarter (32 KiB: 4 kt of one sel) of B into sB (8-wave version).
// LDS dest is wave-uniform base (+ lane*16 by HW); global src is per-lane.
__device__ __forceinline__ void stage4(const uint32_t* Wpk, uint32_t (*sB)[2048],
                                       int wid, int lane, int sel, int half){
    #pragma unroll
    for (int i = 0; i < 4; ++i){
        int ch = wid * 4 + i;                        // 32 chunks of 1 KiB
        int ktv = ch >> 3, part = ch & 7;
        __builtin_amdgcn_global_load_lds(
            Wpk + (size_t)(half * 4 + ktv) * 4096 + sel * 2048 + part * 256 + lane * 4,
            &sB[ktv][part * 256], 16, 0, 0);
    }
}

// ---------- MFMA dual-GEMM (K=256 = [mean|own]) + L2-normalize ----------
// 512 threads = 8 waves; each wave owns 16 rows (ONE m-tile), all 128 cols.
// R6 post-mortem: 32-rows/wave needs ~172 combined VGPR+AGPR -> only 1 block/CU
// resident -> latency-bound at 14% occupancy.  16 rows/wave: A-frags 8-12 bf16x8
// (32-48 V) + acc 8 f32x4 (32 A) ~ 110 combined < 128 -> launch_bounds(512,4)
// pins 4 waves/SIMD = 2 blocks/CU = 16 waves/CU without spilling.
// B staged in FOUR 32 KiB quarters (hi/lo x K-halves) through one 32 KiB buffer.
// A frag:  lane holds row (lane&15), k = 32*kt + 8*(lane>>4) + e  (contiguous 16B)
// B frag:  swizzled slot; gx = g ^ ((l15>>1)&3)   (conflict-free ds_read_b128)
// C/D:     col = lane&15, row = 4*(lane>>4) + reg   (m89-verified)
// MODE 0: own=Xbf (+Xlo correction on hi); out=relu(norm(.)); Hbf store + BN sums.
// MODE 1: own=Hbf (BN folded into Wpk/bias); out=norm(.); Emb f32 + preds.
template<int MODE>
__global__ __launch_bounds__(512, 4) void k_gemm(
        const uint32_t* Own,                 // MODE0: Xbf in Emb rows (stride 128); MODE1: Hbf (stride 64)
        const uint32_t* OwnLo,               // MODE0 only: Xlo (stride 64; aliases HbfOut)
        const uint32_t* Mb,                  // bf16 means at Emb rows' 2nd half
        const uint32_t* __restrict__ Wpk,    // packed+swizzled [kt][hi/lo][512 slots][8] u16
        const float* __restrict__ bias,      // [128] effective bias
        uint32_t* HbfOut,                    // MODE0 out (aliases OwnLo; alias-safe per-wave)
        float* Emb,                          // MODE1 out (aliases Mb rows; reads precede writes)
        float* __restrict__ bnsum, float* __restrict__ bnsumsq,             // MODE0
        const float* __restrict__ fcW, const float* __restrict__ fcb,       // MODE1
        float* __restrict__ preds, int N){
    __shared__ uint32_t __align__(16) sB[4][2048];   // 32 KiB; reused 4x; aliased by lsum/lsq at end
    const int lane = threadIdx.x & 63;
    const int wid  = threadIdx.x >> 6;               // 0..7
    const int l15  = lane & 15;
    const int g    = lane >> 4;
    const int gx4  = (g ^ ((l15 >> 1) & 3)) * 4;     // swizzled 16B sub-slot (u32 units)
    const int ostr = (MODE == 0) ? 128 : 64;
    const int wrow = blockIdx.x * 128 + wid * 16;    // this wave's 16-row m-tile

    stage4(Wpk, sB, wid, lane, 0, 0);                // quarter 1: hi, kt 0-3

    int ar0 = wrow + l15; if (ar0 >= N) ar0 = N - 1; // clamped dup rows: discarded

    const uint32_t* mp0 = Mb  + (size_t)ar0 * 128 + 64 + g * 4;
    const uint32_t* op0 = Own + (size_t)ar0 * ostr + g * 4;

    // hoist ALL A fragments into registers (independent loads, overlap staging)
    bf16x8 am[4], ao[4];
    #pragma unroll
    for (int kq = 0; kq < 4; ++kq){
        am[kq] = *(const bf16x8*)(mp0 + kq * 16);
        ao[kq] = *(const bf16x8*)(op0 + kq * 16);
    }
    bf16x8 xl[4];
    if (MODE == 0){
        #pragma unroll
        for (int kq = 0; kq < 4; ++kq)
            xl[kq] = *(const bf16x8*)(OwnLo + (size_t)ar0 * 64 + g * 4 + kq * 16);
    }

    f32x4 acc[8];
    const f32x4 zero = {0.f, 0.f, 0.f, 0.f};
    #pragma unroll
    for (int t = 0; t < 8; ++t) acc[t] = zero;

#define COMPUTE4(AM, ADD_XLO)                                                 \
    _Pragma("unroll")                                                         \
    for (int kk = 0; kk < 4; ++kk){                                           \
        _Pragma("unroll")                                                     \
        for (int t = 0; t < 8; ++t){                                          \
            bf16x8 bq = *(const bf16x8*)(&sB[kk][(t * 16 + l15) * 16 + gx4]); \
            acc[t] = MFMA(AM[kk], bq, acc[t]);                                \
            if (ADD_XLO) acc[t] = MFMA(xl[kk], bq, acc[t]);                   \
        }                                                                     \
    }

    __syncthreads();                                 // q1 staged + A-loads issued
    COMPUTE4(am, false);                             // hi, kt 0-3 (mean half)
    __syncthreads();
    stage4(Wpk, sB, wid, lane, 0, 1);                // quarter 2: hi, kt 4-7
    __syncthreads();
    COMPUTE4(ao, (MODE == 0));                       // hi, kt 4-7 (own half, +xlo)
    __syncthreads();
    stage4(Wpk, sB, wid, lane, 1, 0);                // quarter 3: lo, kt 0-3
    __syncthreads();
    COMPUTE4(am, false);                             // lo, kt 0-3
    __syncthreads();
    stage4(Wpk, sB, wid, lane, 1, 1);                // quarter 4: lo, kt 4-7
    __syncthreads();
    COMPUTE4(ao, false);                             // lo, kt 4-7
#undef COMPUTE4

    // ---- epilogue ----
    float bv[8];
    #pragma unroll
    for (int t = 0; t < 8; ++t) bv[t] = bias[t * 16 + l15];

    float fw[4]; float fb = 0.f;
    if (MODE == 1){
        #pragma unroll
        for (int t = 0; t < 4; ++t) fw[t] = fcW[t * 16 + l15];
        fb = fcb[0];
    }

    float pbs[8], pbq[8];
    #pragma unroll
    for (int t = 0; t < 8; ++t){ pbs[t] = 0.f; pbq[t] = 0.f; }

    #pragma unroll
    for (int j = 0; j < 4; ++j){
        int orow = wrow + 4 * g + j;
        bool valid = orow < N;
        float o[8]; float ss = 0.f;
        #pragma unroll
        for (int t = 0; t < 8; ++t){
            o[t] = acc[t][j] + bv[t];
            ss += o[t] * o[t];
        }
        ss += __shfl_xor(ss, 1, 64);
        ss += __shfl_xor(ss, 2, 64);
        ss += __shfl_xor(ss, 4, 64);
        ss += __shfl_xor(ss, 8, 64);
        float inv = 1.0f / fmaxf(sqrtf(ss), 1e-12f);
        if (MODE == 0){
            #pragma unroll
            for (int t = 0; t < 8; ++t){
                float v = fmaxf(o[t] * inv, 0.f);
                float pv = __shfl_xor(v, 1, 64);              // partner col (uniform exec)
                if (valid){
                    pbs[t] += v; pbq[t] += v * v;
                    if (!(lane & 1))
                        HbfOut[(size_t)orow * 64 + t * 8 + (l15 >> 1)] = packbf(v, pv);
                }
            }
        } else {
            float p = 0.f;
            #pragma unroll
            for (int t = 0; t < 8; ++t){
                float v = o[t] * inv;
                if (valid) Emb[(size_t)orow * 128 + t * 16 + l15] = v;
                if (t < 4) p += v * fw[t];
            }
            p += __shfl_xor(p, 1, 64);
            p += __shfl_xor(p, 2, 64);
            p += __shfl_xor(p, 4, 64);
            p += __shfl_xor(p, 8, 64);
            if (valid && l15 == 0) preds[orow] = p + fb;
        }
    }

    if (MODE == 0){
        float* lsum = (float*)&sB[0][0];             // sB dead after last compute
        float* lsq  = lsum + 128;
        #pragma unroll
        for (int t = 0; t < 8; ++t){
            pbs[t] += __shfl_xor(pbs[t], 16, 64);
            pbs[t] += __shfl_xor(pbs[t], 32, 64);
            pbq[t] += __shfl_xor(pbq[t], 16, 64);
            pbq[t] += __shfl_xor(pbq[t], 32, 64);
        }
        __syncthreads();                             // all waves done reading sB
        if (threadIdx.x < 128){ lsum[threadIdx.x] = 0.f; lsq[threadIdx.x] = 0.f; }
        __syncthreads();
        if (lane < 16){
            #pragma unroll
            for (int t = 0; t < 8; ++t){
                atomicAdd(&lsum[t * 16 + lane], pbs[t]);
                atomicAdd(&lsq [t * 16 + lane], pbq[t]);
            }
        }
        __syncthreads();
        if (threadIdx.x < 128){
            atomicAdd(&bnsum[threadIdx.x],   lsum[threadIdx.x]);
            atomicAdd(&bnsumsq[threadIdx.x], lsq[threadIdx.x]);
        }
    }
}

// ---------- BN finalize + effective layer-2 bias (b2 + shift @ W2r) ----------
__global__ void k_bnfinal(const float* __restrict__ bnsum, const float* __restrict__ bnsumsq,
                          const float* __restrict__ gamma, const float* __restrict__ beta,
                          const float* __restrict__ W2r, const float* __restrict__ b2,
                          float* __restrict__ scale, float* __restrict__ shift,
                          float* __restrict__ bias2, int N){
    __shared__ float sh_l[128];
    int t = threadIdx.x;
    float invN = 1.0f / (float)N;
    float mu  = bnsum[t] * invN;
    float var = fmaxf(bnsumsq[t] * invN - mu * mu, 0.f);
    float istd = 1.0f / sqrtf(var + 1e-5f);
    float sc = gamma[t] * istd;
    float sf = beta[t] - mu * sc;
    scale[t] = sc; shift[t] = sf; sh_l[t] = sf;
    __syncthreads();
    float acc = b2[t];
    for (int k = 0; k < 128; ++k) acc += sh_l[k] * W2r[k * 128 + t];
    bias2[t] = acc;
}

__global__ void k_sent(float* __restrict__ preds, int N, float val){
    int i = blockIdx.x * 256 + threadIdx.x;
    if (i < N) preds[i] = val;
}

// ---------- launch ----------
extern "C" void kernel_launch(void* const* d_in, const int* in_sizes, int n_in,
                              void* d_out, int out_size, void* d_ws, size_t ws_size,
                              hipStream_t stream){
    const int N = in_sizes[0] / 128;
    const int E = in_sizes[1] / 2;

    const float* x    = (const float*)d_in[0];
    const int*   ei   = (const int*)d_in[1];
    const int*   src  = ei;
    const int*   dst  = ei + E;
    const float* W1l  = (const float*)d_in[2];
    const float* b1   = (const float*)d_in[3];
    const float* W1r  = (const float*)d_in[4];
    const float* gam  = (const float*)d_in[5];
    const float* bet  = (const float*)d_in[6];
    const float* W2l  = (const float*)d_in[7];
    const float* b2   = (const float*)d_in[8];
    const float* W2r  = (const float*)d_in[9];
    const float* fcW  = (const float*)d_in[10];
    const float* fcb  = (const float*)d_in[11];

    float* preds = (float*)d_out;                 // f32 [N]
    float* Emb   = preds + N;                     // f32 [N,128]
    uint32_t* EmbU = (uint32_t*)Emb;              // Xbf (1st half) + Mb (2nd half) scratch

    char* w = (char*)d_ws;
    auto carve = [&](size_t bytes){ char* p = w; w += (bytes + 255) & ~(size_t)255; return p; };
    int*   counts  = (int*)  carve((size_t)N * 8);   // counts[N] + cursor[N], one memset
    int*   cursor  = counts + N;
    int*   offs    = (int*)  carve((size_t)N * 4);
    int*   bsums   = (int*)  carve(256 * 4);
    float* bnsum   = (float*)carve(128 * 4);      // contiguous with bnsumsq (one memset)
    float* bnsumsq = (float*)carve(128 * 4);
    float* bnscale = (float*)carve(128 * 4);
    float* bnshift = (float*)carve(128 * 4);
    float* bias2   = (float*)carve(128 * 4);
    int*   ssrc    = (int*)  carve((size_t)E * 4);
    uint32_t* HbfXlo = (uint32_t*)carve((size_t)N * 256);  // Xlo then Hbf (overlay, alias-safe)
    uint16_t* Wpk1 = (uint16_t*)carve(131072);    // packed+swizzled [kt][hi/lo][512][8]
    uint16_t* Wpk2 = (uint16_t*)carve(131072);
    size_t need = (size_t)(w - (char*)d_ws);
    if (ws_size < need){
        float val = 1024.f + 4.f * (float)((ws_size >> 20) > 255 ? 255 : (ws_size >> 20));
        k_sent<<<(N + 255) / 256, 256, 0, stream>>>(preds, N, val);
        return;
    }

    hipMemsetAsync(counts, 0, (size_t)N * 8, stream);
    hipMemsetAsync(bnsum,  0, 1024, stream);

    const int eb = (E + 255) / 256;
    const int NB = (N + 2047) / 2048;
    const int ab = (N + 3) / 4;
    const int gb = (N + 127) / 128;
    const int xb = (N * 32 + 255) / 256;

    k_deg  <<<eb, 256, 0, stream>>>(dst, counts, E);
    k_scan1<<<NB, 256, 0, stream>>>(counts, bsums, N);
    k_scan2<<<1,    1, 0, stream>>>(bsums, NB);
    k_scan3<<<NB, 256, 0, stream>>>(counts, bsums, offs, N);
    k_fill <<<eb, 256, 0, stream>>>(src, dst, offs, cursor, ssrc, E);

    k_x2bf <<<xb, 256, 0, stream>>>(x, EmbU, HbfXlo, N);
    k_wprep<<<128, 256, 0, stream>>>(W1l, W1r, nullptr, Wpk1);

    // layer 1
    k_agg<0> <<<ab, 256, 0, stream>>>(EmbU, 128, offs, counts, ssrc,
                                      nullptr, nullptr, EmbU, N);
    k_gemm<0><<<gb, 512, 0, stream>>>(EmbU, HbfXlo, EmbU, (const uint32_t*)Wpk1, b1,
                                      HbfXlo, nullptr, bnsum, bnsumsq,
                                      nullptr, nullptr, nullptr, N);
    k_bnfinal<<<1, 128, 0, stream>>>(bnsum, bnsumsq, gam, bet, W2r, b2,
                                     bnscale, bnshift, bias2, N);
    k_wprep<<<128, 256, 0, stream>>>(W2l, W2r, bnscale, Wpk2);

    // layer 2
    k_agg<1> <<<ab, 256, 0, stream>>>(HbfXlo, 64, offs, counts, ssrc,
                                      bnscale, bnshift, EmbU, N);
    k_gemm<1><<<gb, 512, 0, stream>>>(HbfXlo, nullptr, EmbU, (const uint32_t*)Wpk2, bias2,
                                      nullptr, Emb, nullptr, nullptr,
                                      fcW, fcb, preds, N);
}